// Round 9
// baseline (332.573 us; speedup 1.0000x reference)
//
#include <hip/hip_runtime.h>
#include <hip/hip_bf16.h>

typedef _Float16 half8 __attribute__((ext_vector_type(8)));
typedef _Float16 half2v __attribute__((ext_vector_type(2)));
typedef __fp16 fp16x2 __attribute__((ext_vector_type(2)));
typedef float f32x4 __attribute__((ext_vector_type(4)));
typedef int i32x4 __attribute__((ext_vector_type(4)));

#define BH_ 64
#define L_ 1024
#define DK_ 64

__device__ __forceinline__ unsigned short f2h(float f) {
    _Float16 h = (_Float16)f;
    return __builtin_bit_cast(unsigned short, h);
}
__device__ __forceinline__ unsigned int pk2h(float a, float b) {
    fp16x2 h = __builtin_amdgcn_cvt_pkrtz(a, b);
    return __builtin_bit_cast(unsigned int, h);
}

template<int OFF>
__device__ __forceinline__ void gl_h8(half8& d, const unsigned short* p) {
    asm volatile("global_load_dwordx4 %0, %1, off offset:%2"
                 : "=&v"(d) : "v"(p), "n"(OFF));
}
template<int OFF>
__device__ __forceinline__ void gl_i4(i32x4& d, const int* p) {
    asm volatile("global_load_dwordx4 %0, %1, off offset:%2"
                 : "=&v"(d) : "v"(p), "n"(OFF));
}
template<int OFF>
__device__ __forceinline__ void gl_f4(f32x4& d, const float* p) {
    asm volatile("global_load_dwordx4 %0, %1, off offset:%2"
                 : "=&v"(d) : "v"(p), "n"(OFF));
}
template<int N>
__device__ __forceinline__ void wait_vm() {
    asm volatile("s_waitcnt vmcnt(%0)" :: "n"(N) : "memory");
    __builtin_amdgcn_sched_barrier(0);
}

// ---------------- prep: K -> fp16 ----------------
__global__ void prep_k(const float* __restrict__ K, unsigned short* __restrict__ Kh) {
    int idx = blockIdx.x * 256 + threadIdx.x;
    float4 v = reinterpret_cast<const float4*>(K)[idx];
    ushort4 o;
    o.x = f2h(v.x); o.y = f2h(v.y); o.z = f2h(v.z); o.w = f2h(v.w);
    reinterpret_cast<ushort4*>(Kh)[idx] = o;
}

// ---------------- prep: V -> Vt fp16 transposed [bh][n][k] ----------------
__global__ void prep_v(const float* __restrict__ V, unsigned short* __restrict__ Vt) {
    __shared__ float lds[64][65];
    int bh = blockIdx.x >> 4, kt = blockIdx.x & 15;
    int t = threadIdx.x;
    const float* Vb = V + ((size_t)bh * L_ + kt * 64) * DK_;
#pragma unroll
    for (int it = 0; it < 4; ++it) {
        int idx = it * 256 + t;
        int row = idx >> 4, c4 = idx & 15;
        float4 v = reinterpret_cast<const float4*>(Vb + (size_t)row * DK_)[c4];
        lds[row][c4 * 4 + 0] = v.x; lds[row][c4 * 4 + 1] = v.y;
        lds[row][c4 * 4 + 2] = v.z; lds[row][c4 * 4 + 3] = v.w;
    }
    __syncthreads();
    unsigned short* Vtb = Vt + (size_t)bh * 64 * L_ + kt * 64;
#pragma unroll
    for (int it = 0; it < 4; ++it) {
        int idx = it * 256 + t;
        int n = idx >> 4, c4 = idx & 15;
        ushort4 o;
        o.x = f2h(lds[c4 * 4 + 0][n]);
        o.y = f2h(lds[c4 * 4 + 1][n]);
        o.z = f2h(lds[c4 * 4 + 2][n]);
        o.w = f2h(lds[c4 * 4 + 3][n]);
        *reinterpret_cast<ushort4*>(Vtb + (size_t)n * L_ + c4 * 4) = o;
    }
}

// ================= variant A: R8 asm pipeline (control), bh 0-21 =========
__global__ __launch_bounds__(256, 4) void attn_a(
    const float* __restrict__ Q, const int* __restrict__ mask,
    const unsigned short* __restrict__ Kh, const unsigned short* __restrict__ Vt,
    float* __restrict__ ctx_out, float* __restrict__ attn_out)
{
    const int qt = blockIdx.x, bh = blockIdx.y;
    const int tid = threadIdx.x;
    const int w = tid >> 6;
    const int lane = tid & 63;
    const int lg = lane >> 4, lr = lane & 15;
    const int q0 = qt * 16;

    __shared__ float red[2][4][16];
    __shared__ union {
        unsigned short pbuf[4][640];
        float ctxbuf[4][16][68];
    } u;

    const size_t rowbase = ((size_t)bh * L_ + q0 + lr) * L_;
    const float* qp = Q + ((size_t)bh * L_ + q0 + lr) * DK_ + lg * 8;
    const int* mp = mask + rowbase + w * 256 + lg * 4;
    const unsigned short* kp = Kh + ((size_t)bh * L_ + w * 256 + lr) * DK_ + lg * 8;

    i32x4 mreg[8];
    half8 ka[2][2], kb[2][2];
#define ISSUE_K2(BUF, C) { \
    const unsigned short* a_ = kp + (C) * 2048; \
    gl_h8<0>(ka[BUF][0], a_);    gl_h8<64>(kb[BUF][0], a_); \
    gl_h8<2048>(ka[BUF][1], a_); gl_h8<2112>(kb[BUF][1], a_); }
#define ISSUE_M4(IDX, T) { \
    gl_i4<(T) * 64 + 0>(mreg[(IDX) + 0], mp); \
    gl_i4<(T) * 64 + 64>(mreg[(IDX) + 1], mp); \
    gl_i4<(T) * 64 + 128>(mreg[(IDX) + 2], mp); \
    gl_i4<(T) * 64 + 192>(mreg[(IDX) + 3], mp); }
#define PACK_M4(DST, IDX) { \
    DST = 0; \
    _Pragma("unroll") \
    for (int t = 0; t < 4; ++t) \
        DST |= (unsigned(mreg[(IDX) + t][0] != 0) << (t * 4 + 0)) \
             | (unsigned(mreg[(IDX) + t][1] != 0) << (t * 4 + 1)) \
             | (unsigned(mreg[(IDX) + t][2] != 0) << (t * 4 + 2)) \
             | (unsigned(mreg[(IDX) + t][3] != 0) << (t * 4 + 3)); }

    ISSUE_M4(0, 0);
    ISSUE_M4(4, 4);
    f32x4 qf0, qf1, qf2, qf3;
    gl_f4<0>(qf0, qp); gl_f4<16>(qf1, qp);
    gl_f4<128>(qf2, qp); gl_f4<144>(qf3, qp);
    ISSUE_K2(0, 0);
    ISSUE_K2(1, 1);

    unsigned int mwA, mwB, mwC, mwD, mw0, mw1;
    wait_vm<16>();
    PACK_M4(mwA, 0);
    wait_vm<12>();
    PACK_M4(mwB, 4);
    mw0 = mwA | (mwB << 16);
    wait_vm<8>();
    half8 qh[2];
#pragma unroll
    for (int j = 0; j < 4; ++j) {
        qh[0][j]     = (_Float16)qf0[j];
        qh[0][j + 4] = (_Float16)qf1[j];
        qh[1][j]     = (_Float16)qf2[j];
        qh[1][j + 4] = (_Float16)qf3[j];
    }

    unsigned int sh[16][2];
    float mx = -INFINITY;
#define QK_TILE(BUF, T, TT, WORD) { \
    f32x4 acc_ = {0.f, 0.f, 0.f, 0.f}; \
    acc_ = __builtin_amdgcn_mfma_f32_16x16x32_f16(ka[BUF][T], qh[0], acc_, 0, 0, 0); \
    acc_ = __builtin_amdgcn_mfma_f32_16x16x32_f16(kb[BUF][T], qh[1], acc_, 0, 0, 0); \
    float s0_ = (((WORD) >> (((TT) & 7) * 4 + 0)) & 1u) ? -INFINITY : 0.25f * acc_[0]; \
    float s1_ = (((WORD) >> (((TT) & 7) * 4 + 1)) & 1u) ? -INFINITY : 0.25f * acc_[1]; \
    float s2_ = (((WORD) >> (((TT) & 7) * 4 + 2)) & 1u) ? -INFINITY : 0.25f * acc_[2]; \
    float s3_ = (((WORD) >> (((TT) & 7) * 4 + 3)) & 1u) ? -INFINITY : 0.25f * acc_[3]; \
    sh[TT][0] = pk2h(s0_, s1_); sh[TT][1] = pk2h(s2_, s3_); \
    mx = fmaxf(mx, fmaxf(fmaxf(s0_, s1_), fmaxf(s2_, s3_))); }
#define QK2(BUF, TT0, WORD) { \
    QK_TILE(BUF, 0, TT0, WORD); QK_TILE(BUF, 1, (TT0) + 1, WORD); }

    wait_vm<4>();
    QK2(0, 0, mw0);
    ISSUE_K2(0, 2);
    wait_vm<4>();
    QK2(1, 2, mw0);
    ISSUE_M4(0, 8);
    ISSUE_K2(1, 3);
    wait_vm<8>();
    QK2(0, 4, mw0);
    ISSUE_M4(4, 12);
    ISSUE_K2(0, 4);
    wait_vm<12>();
    PACK_M4(mwC, 0);
    wait_vm<8>();
    QK2(1, 6, mw0);
    ISSUE_K2(1, 5);
    wait_vm<8>();
    PACK_M4(mwD, 4);
    mw1 = mwC | (mwD << 16);
    wait_vm<4>();
    QK2(0, 8, mw1);
    ISSUE_K2(0, 6);
    wait_vm<4>();
    QK2(1, 10, mw1);
    ISSUE_K2(1, 7);
    wait_vm<4>();
    QK2(0, 12, mw1);
    wait_vm<0>();
    QK2(1, 14, mw1);

    mx = fmaxf(mx, __shfl_xor(mx, 16));
    mx = fmaxf(mx, __shfl_xor(mx, 32));
    if (lane < 16) red[0][w][lr] = mx;
    __syncthreads();
    const float gm = fmaxf(fmaxf(red[0][0][lr], red[0][1][lr]),
                           fmaxf(red[0][2][lr], red[0][3][lr]));

    float lsum = 0.f;
#pragma unroll
    for (int tt = 0; tt < 16; ++tt) {
        half2v a = __builtin_bit_cast(half2v, sh[tt][0]);
        half2v b = __builtin_bit_cast(half2v, sh[tt][1]);
        float p0 = __expf((float)a[0] - gm);
        float p1 = __expf((float)a[1] - gm);
        float p2 = __expf((float)b[0] - gm);
        float p3 = __expf((float)b[1] - gm);
        lsum += (p0 + p1) + (p2 + p3);
        sh[tt][0] = pk2h(p0, p1);
        sh[tt][1] = pk2h(p2, p3);
    }
    lsum += __shfl_xor(lsum, 16);
    lsum += __shfl_xor(lsum, 32);
    if (lane < 16) red[1][w][lr] = lsum;
    __syncthreads();
    const float gsum = red[1][0][lr] + red[1][1][lr] + red[1][2][lr] + red[1][3][lr];
    const float rinv = 1.0f / gsum;

    const unsigned short* vp = Vt + ((size_t)bh * 64 + lr) * L_ + w * 256 + lg * 8;
    const unsigned short* vp0 = vp;
    const unsigned short* vp1 = vp + 16384;
    const unsigned short* vp2 = vp + 32768;
    const unsigned short* vp3 = vp + 49152;
    f32x4 cacc[4] = {{0,0,0,0},{0,0,0,0},{0,0,0,0},{0,0,0,0}};
    unsigned short* pb = &u.pbuf[w][0];
    half8 vv[2][4];
#define ISSUE_V1(BUF, C) { \
    gl_h8<(C) * 64>(vv[BUF][0], vp0); gl_h8<(C) * 64>(vv[BUF][1], vp1); \
    gl_h8<(C) * 64>(vv[BUF][2], vp2); gl_h8<(C) * 64>(vv[BUF][3], vp3); }
#define PV_C(BUF, C) { \
    uint2 pr0_; pr0_.x = sh[2 * (C)][0]; pr0_.y = sh[2 * (C)][1]; \
    *reinterpret_cast<uint2*>(&pb[lr * 40 + lg * 4]) = pr0_; \
    uint2 pr1_; pr1_.x = sh[2 * (C) + 1][0]; pr1_.y = sh[2 * (C) + 1][1]; \
    *reinterpret_cast<uint2*>(&pb[lr * 40 + 16 + lg * 4]) = pr1_; \
    half8 pa_ = *reinterpret_cast<const half8*>(&pb[lr * 40 + lg * 8]); \
    cacc[0] = __builtin_amdgcn_mfma_f32_16x16x32_f16(pa_, vv[BUF][0], cacc[0], 0, 0, 0); \
    cacc[1] = __builtin_amdgcn_mfma_f32_16x16x32_f16(pa_, vv[BUF][1], cacc[1], 0, 0, 0); \
    cacc[2] = __builtin_amdgcn_mfma_f32_16x16x32_f16(pa_, vv[BUF][2], cacc[2], 0, 0, 0); \
    cacc[3] = __builtin_amdgcn_mfma_f32_16x16x32_f16(pa_, vv[BUF][3], cacc[3], 0, 0, 0); }

    ISSUE_V1(0, 0); ISSUE_V1(1, 1);
    wait_vm<4>(); PV_C(0, 0); ISSUE_V1(0, 2);
    wait_vm<4>(); PV_C(1, 1); ISSUE_V1(1, 3);
    wait_vm<4>(); PV_C(0, 2); ISSUE_V1(0, 4);
    wait_vm<4>(); PV_C(1, 3); ISSUE_V1(1, 5);
    wait_vm<4>(); PV_C(0, 4); ISSUE_V1(0, 6);
    wait_vm<4>(); PV_C(1, 5); ISSUE_V1(1, 7);
    wait_vm<4>(); PV_C(0, 6);
    wait_vm<0>(); PV_C(1, 7);

#pragma unroll
    for (int tt = 0; tt < 16; ++tt) {
        half2v a = __builtin_bit_cast(half2v, sh[tt][0]);
        half2v b = __builtin_bit_cast(half2v, sh[tt][1]);
        float4 av;
        av.x = (float)a[0] * rinv; av.y = (float)a[1] * rinv;
        av.z = (float)b[0] * rinv; av.w = (float)b[1] * rinv;
        *reinterpret_cast<float4*>(&attn_out[rowbase + w * 256 + tt * 16 + lg * 4]) = av;
    }

    __syncthreads();
#pragma unroll
    for (int nt = 0; nt < 4; ++nt)
#pragma unroll
        for (int r = 0; r < 4; ++r)
            u.ctxbuf[w][lg * 4 + r][nt * 16 + lr] = cacc[nt][r];
    __syncthreads();
    {
        int e = tid * 4;
        int q = e >> 6, n = e & 63;
        float gs = red[1][0][q] + red[1][1][q] + red[1][2][q] + red[1][3][q];
        float rq = 1.0f / gs;
        float4 a0 = *reinterpret_cast<float4*>(&u.ctxbuf[0][q][n]);
        float4 a1 = *reinterpret_cast<float4*>(&u.ctxbuf[1][q][n]);
        float4 a2 = *reinterpret_cast<float4*>(&u.ctxbuf[2][q][n]);
        float4 a3 = *reinterpret_cast<float4*>(&u.ctxbuf[3][q][n]);
        float4 o;
        o.x = (a0.x + a1.x + a2.x + a3.x) * rq;
        o.y = (a0.y + a1.y + a2.y + a3.y) * rq;
        o.z = (a0.z + a1.z + a2.z + a3.z) * rq;
        o.w = (a0.w + a1.w + a2.w + a3.w) * rq;
        *reinterpret_cast<float4*>(&ctx_out[((size_t)bh * L_ + q0 + q) * DK_ + n]) = o;
    }
#undef ISSUE_K2
#undef ISSUE_M4
#undef PACK_M4
#undef QK_TILE
#undef QK2
#undef ISSUE_V1
#undef PV_C
}

// ======== variant B: plain HIP (R4 body), launch_bounds(256,8), bh 22-42 ====
__global__ __launch_bounds__(256, 8) void attn_b(
    const float* __restrict__ Q, const int* __restrict__ mask,
    const unsigned short* __restrict__ Kh, const unsigned short* __restrict__ Vt,
    float* __restrict__ ctx_out, float* __restrict__ attn_out)
{
    const int qt = blockIdx.x, bh = blockIdx.y + 22;
    const int tid = threadIdx.x;
    const int w = tid >> 6;
    const int lane = tid & 63;
    const int lg = lane >> 4, lr = lane & 15;
    const int q0 = qt * 16;

    __shared__ float red[2][4][16];
    __shared__ union {
        unsigned short pbuf[4][640];
        float ctxbuf[4][16][68];
    } u;

    half8 qh[2];
    {
        const float* qp = Q + ((size_t)bh * L_ + q0 + lr) * DK_ + lg * 8;
#pragma unroll
        for (int f = 0; f < 2; ++f) {
            float4 a = *reinterpret_cast<const float4*>(qp + f * 32);
            float4 b = *reinterpret_cast<const float4*>(qp + f * 32 + 4);
            qh[f][0] = (_Float16)a.x; qh[f][1] = (_Float16)a.y;
            qh[f][2] = (_Float16)a.z; qh[f][3] = (_Float16)a.w;
            qh[f][4] = (_Float16)b.x; qh[f][5] = (_Float16)b.y;
            qh[f][6] = (_Float16)b.z; qh[f][7] = (_Float16)b.w;
        }
    }

    const size_t rowbase = ((size_t)bh * L_ + q0 + lr) * L_;
    const int* mp = mask + rowbase + w * 256 + lg * 4;
    const unsigned short* kp = Kh + ((size_t)bh * L_ + w * 256 + lr) * DK_ + lg * 8;

    unsigned int sh[16][2];
    float mx = -INFINITY;

    half8 kc0 = *reinterpret_cast<const half8*>(kp);
    half8 kc1 = *reinterpret_cast<const half8*>(kp + 32);
    int4 m0 = *reinterpret_cast<const int4*>(mp);
    int4 m1 = *reinterpret_cast<const int4*>(mp + 16);

#pragma unroll
    for (int tt = 0; tt < 16; ++tt) {
        half8 kn0 = kc0, kn1 = kc1;
        int4 mn = m1;
        if (tt < 15) {
            kn0 = *reinterpret_cast<const half8*>(kp + (tt + 1) * 1024);
            kn1 = *reinterpret_cast<const half8*>(kp + (tt + 1) * 1024 + 32);
        }
        if (tt < 14) mn = *reinterpret_cast<const int4*>(mp + (tt + 2) * 16);
        f32x4 acc = {0.f, 0.f, 0.f, 0.f};
        acc = __builtin_amdgcn_mfma_f32_16x16x32_f16(kc0, qh[0], acc, 0, 0, 0);
        acc = __builtin_amdgcn_mfma_f32_16x16x32_f16(kc1, qh[1], acc, 0, 0, 0);
        float s0 = m0.x ? -INFINITY : 0.25f * acc[0];
        float s1 = m0.y ? -INFINITY : 0.25f * acc[1];
        float s2 = m0.z ? -INFINITY : 0.25f * acc[2];
        float s3 = m0.w ? -INFINITY : 0.25f * acc[3];
        sh[tt][0] = pk2h(s0, s1);
        sh[tt][1] = pk2h(s2, s3);
        mx = fmaxf(mx, fmaxf(fmaxf(s0, s1), fmaxf(s2, s3)));
        kc0 = kn0; kc1 = kn1; m0 = m1; m1 = mn;
    }

    mx = fmaxf(mx, __shfl_xor(mx, 16));
    mx = fmaxf(mx, __shfl_xor(mx, 32));
    if (lane < 16) red[0][w][lr] = mx;
    __syncthreads();
    const float gm = fmaxf(fmaxf(red[0][0][lr], red[0][1][lr]),
                           fmaxf(red[0][2][lr], red[0][3][lr]));

    float lsum = 0.f;
#pragma unroll
    for (int tt = 0; tt < 16; ++tt) {
        half2v a = __builtin_bit_cast(half2v, sh[tt][0]);
        half2v b = __builtin_bit_cast(half2v, sh[tt][1]);
        float p0 = __expf((float)a[0] - gm);
        float p1 = __expf((float)a[1] - gm);
        float p2 = __expf((float)b[0] - gm);
        float p3 = __expf((float)b[1] - gm);
        lsum += (p0 + p1) + (p2 + p3);
        sh[tt][0] = pk2h(p0, p1);
        sh[tt][1] = pk2h(p2, p3);
    }
    lsum += __shfl_xor(lsum, 16);
    lsum += __shfl_xor(lsum, 32);
    if (lane < 16) red[1][w][lr] = lsum;
    __syncthreads();
    const float gsum = red[1][0][lr] + red[1][1][lr] + red[1][2][lr] + red[1][3][lr];
    const float rinv = 1.0f / gsum;

    f32x4 cacc[4] = {{0,0,0,0},{0,0,0,0},{0,0,0,0},{0,0,0,0}};
    unsigned short* pb = &u.pbuf[w][0];
    const unsigned short* vp = Vt + ((size_t)bh * 64 + lr) * L_ + w * 256 + lg * 8;

    half8 vb0 = *reinterpret_cast<const half8*>(vp);
    half8 vb1 = *reinterpret_cast<const half8*>(vp + 16384);
    half8 vb2 = *reinterpret_cast<const half8*>(vp + 32768);
    half8 vb3 = *reinterpret_cast<const half8*>(vp + 49152);

#pragma unroll
    for (int c = 0; c < 8; ++c) {
        half8 vn0 = vb0, vn1 = vb1, vn2 = vb2, vn3 = vb3;
        if (c < 7) {
            vn0 = *reinterpret_cast<const half8*>(vp + (c + 1) * 32);
            vn1 = *reinterpret_cast<const half8*>(vp + 16384 + (c + 1) * 32);
            vn2 = *reinterpret_cast<const half8*>(vp + 32768 + (c + 1) * 32);
            vn3 = *reinterpret_cast<const half8*>(vp + 49152 + (c + 1) * 32);
        }
#pragma unroll
        for (int t2 = 0; t2 < 2; ++t2) {
            const int tt = 2 * c + t2;
            uint2 pr; pr.x = sh[tt][0]; pr.y = sh[tt][1];
            *reinterpret_cast<uint2*>(&pb[lr * 40 + t2 * 16 + lg * 4]) = pr;
        }
        half8 pa = *reinterpret_cast<const half8*>(&pb[lr * 40 + lg * 8]);
        cacc[0] = __builtin_amdgcn_mfma_f32_16x16x32_f16(pa, vb0, cacc[0], 0, 0, 0);
        cacc[1] = __builtin_amdgcn_mfma_f32_16x16x32_f16(pa, vb1, cacc[1], 0, 0, 0);
        cacc[2] = __builtin_amdgcn_mfma_f32_16x16x32_f16(pa, vb2, cacc[2], 0, 0, 0);
        cacc[3] = __builtin_amdgcn_mfma_f32_16x16x32_f16(pa, vb3, cacc[3], 0, 0, 0);
        vb0 = vn0; vb1 = vn1; vb2 = vn2; vb3 = vn3;
    }

#pragma unroll
    for (int tt = 0; tt < 16; ++tt) {
        half2v a = __builtin_bit_cast(half2v, sh[tt][0]);
        half2v b = __builtin_bit_cast(half2v, sh[tt][1]);
        float4 av;
        av.x = (float)a[0] * rinv; av.y = (float)a[1] * rinv;
        av.z = (float)b[0] * rinv; av.w = (float)b[1] * rinv;
        *reinterpret_cast<float4*>(&attn_out[rowbase + w * 256 + tt * 16 + lg * 4]) = av;
    }

    __syncthreads();
#pragma unroll
    for (int nt = 0; nt < 4; ++nt)
#pragma unroll
        for (int r = 0; r < 4; ++r)
            u.ctxbuf[w][lg * 4 + r][nt * 16 + lr] = cacc[nt][r];
    __syncthreads();
    {
        int e = tid * 4;
        int q = e >> 6, n = e & 63;
        float gs = red[1][0][q] + red[1][1][q] + red[1][2][q] + red[1][3][q];
        float rq = 1.0f / gs;
        float4 a0 = *reinterpret_cast<float4*>(&u.ctxbuf[0][q][n]);
        float4 a1 = *reinterpret_cast<float4*>(&u.ctxbuf[1][q][n]);
        float4 a2 = *reinterpret_cast<float4*>(&u.ctxbuf[2][q][n]);
        float4 a3 = *reinterpret_cast<float4*>(&u.ctxbuf[3][q][n]);
        float4 o;
        o.x = (a0.x + a1.x + a2.x + a3.x) * rq;
        o.y = (a0.y + a1.y + a2.y + a3.y) * rq;
        o.z = (a0.z + a1.z + a2.z + a3.z) * rq;
        o.w = (a0.w + a1.w + a2.w + a3.w) * rq;
        *reinterpret_cast<float4*>(&ctx_out[((size_t)bh * L_ + q0 + q) * DK_ + n]) = o;
    }
}

// == variant C: 8-wave WG, k-split 128/wave, launch_bounds(512,8), bh 43-63 ==
__global__ __launch_bounds__(512, 8) void attn_c(
    const float* __restrict__ Q, const int* __restrict__ mask,
    const unsigned short* __restrict__ Kh, const unsigned short* __restrict__ Vt,
    float* __restrict__ ctx_out, float* __restrict__ attn_out)
{
    const int qt = blockIdx.x, bh = blockIdx.y + 43;
    const int tid = threadIdx.x;
    const int w = tid >> 6;            // 0..7, owns k in [w*128, w*128+128)
    const int lane = tid & 63;
    const int lg = lane >> 4, lr = lane & 15;
    const int q0 = qt * 16;

    __shared__ float red[2][8][16];
    __shared__ union {
        unsigned short pbuf[8][640];
        float ctxbuf[8][16][68];
    } u;

    half8 qh[2];
    {
        const float* qp = Q + ((size_t)bh * L_ + q0 + lr) * DK_ + lg * 8;
#pragma unroll
        for (int f = 0; f < 2; ++f) {
            float4 a = *reinterpret_cast<const float4*>(qp + f * 32);
            float4 b = *reinterpret_cast<const float4*>(qp + f * 32 + 4);
            qh[f][0] = (_Float16)a.x; qh[f][1] = (_Float16)a.y;
            qh[f][2] = (_Float16)a.z; qh[f][3] = (_Float16)a.w;
            qh[f][4] = (_Float16)b.x; qh[f][5] = (_Float16)b.y;
            qh[f][6] = (_Float16)b.z; qh[f][7] = (_Float16)b.w;
        }
    }

    const size_t rowbase = ((size_t)bh * L_ + q0 + lr) * L_;
    const int* mp = mask + rowbase + w * 128 + lg * 4;
    const unsigned short* kp = Kh + ((size_t)bh * L_ + w * 128 + lr) * DK_ + lg * 8;

    unsigned int sh[8][2];
    float mx = -INFINITY;

    half8 kc0 = *reinterpret_cast<const half8*>(kp);
    half8 kc1 = *reinterpret_cast<const half8*>(kp + 32);
    int4 m0 = *reinterpret_cast<const int4*>(mp);
    int4 m1 = *reinterpret_cast<const int4*>(mp + 16);

#pragma unroll
    for (int tt = 0; tt < 8; ++tt) {
        half8 kn0 = kc0, kn1 = kc1;
        int4 mn = m1;
        if (tt < 7) {
            kn0 = *reinterpret_cast<const half8*>(kp + (tt + 1) * 1024);
            kn1 = *reinterpret_cast<const half8*>(kp + (tt + 1) * 1024 + 32);
        }
        if (tt < 6) mn = *reinterpret_cast<const int4*>(mp + (tt + 2) * 16);
        f32x4 acc = {0.f, 0.f, 0.f, 0.f};
        acc = __builtin_amdgcn_mfma_f32_16x16x32_f16(kc0, qh[0], acc, 0, 0, 0);
        acc = __builtin_amdgcn_mfma_f32_16x16x32_f16(kc1, qh[1], acc, 0, 0, 0);
        float s0 = m0.x ? -INFINITY : 0.25f * acc[0];
        float s1 = m0.y ? -INFINITY : 0.25f * acc[1];
        float s2 = m0.z ? -INFINITY : 0.25f * acc[2];
        float s3 = m0.w ? -INFINITY : 0.25f * acc[3];
        sh[tt][0] = pk2h(s0, s1);
        sh[tt][1] = pk2h(s2, s3);
        mx = fmaxf(mx, fmaxf(fmaxf(s0, s1), fmaxf(s2, s3)));
        kc0 = kn0; kc1 = kn1; m0 = m1; m1 = mn;
    }

    mx = fmaxf(mx, __shfl_xor(mx, 16));
    mx = fmaxf(mx, __shfl_xor(mx, 32));
    if (lane < 16) red[0][w][lr] = mx;
    __syncthreads();
    float gm = red[0][0][lr];
#pragma unroll
    for (int ww = 1; ww < 8; ++ww) gm = fmaxf(gm, red[0][ww][lr]);

    float lsum = 0.f;
#pragma unroll
    for (int tt = 0; tt < 8; ++tt) {
        half2v a = __builtin_bit_cast(half2v, sh[tt][0]);
        half2v b = __builtin_bit_cast(half2v, sh[tt][1]);
        float p0 = __expf((float)a[0] - gm);
        float p1 = __expf((float)a[1] - gm);
        float p2 = __expf((float)b[0] - gm);
        float p3 = __expf((float)b[1] - gm);
        lsum += (p0 + p1) + (p2 + p3);
        sh[tt][0] = pk2h(p0, p1);
        sh[tt][1] = pk2h(p2, p3);
    }
    lsum += __shfl_xor(lsum, 16);
    lsum += __shfl_xor(lsum, 32);
    if (lane < 16) red[1][w][lr] = lsum;
    __syncthreads();
    float gsum = red[1][0][lr];
#pragma unroll
    for (int ww = 1; ww < 8; ++ww) gsum += red[1][ww][lr];
    const float rinv = 1.0f / gsum;

    f32x4 cacc[4] = {{0,0,0,0},{0,0,0,0},{0,0,0,0},{0,0,0,0}};
    unsigned short* pb = &u.pbuf[w][0];
    const unsigned short* vp = Vt + ((size_t)bh * 64 + lr) * L_ + w * 128 + lg * 8;

    half8 vb0 = *reinterpret_cast<const half8*>(vp);
    half8 vb1 = *reinterpret_cast<const half8*>(vp + 16384);
    half8 vb2 = *reinterpret_cast<const half8*>(vp + 32768);
    half8 vb3 = *reinterpret_cast<const half8*>(vp + 49152);

#pragma unroll
    for (int c = 0; c < 4; ++c) {
        half8 vn0 = vb0, vn1 = vb1, vn2 = vb2, vn3 = vb3;
        if (c < 3) {
            vn0 = *reinterpret_cast<const half8*>(vp + (c + 1) * 32);
            vn1 = *reinterpret_cast<const half8*>(vp + 16384 + (c + 1) * 32);
            vn2 = *reinterpret_cast<const half8*>(vp + 32768 + (c + 1) * 32);
            vn3 = *reinterpret_cast<const half8*>(vp + 49152 + (c + 1) * 32);
        }
#pragma unroll
        for (int t2 = 0; t2 < 2; ++t2) {
            const int tt = 2 * c + t2;
            uint2 pr; pr.x = sh[tt][0]; pr.y = sh[tt][1];
            *reinterpret_cast<uint2*>(&pb[lr * 40 + t2 * 16 + lg * 4]) = pr;
        }
        half8 pa = *reinterpret_cast<const half8*>(&pb[lr * 40 + lg * 8]);
        cacc[0] = __builtin_amdgcn_mfma_f32_16x16x32_f16(pa, vb0, cacc[0], 0, 0, 0);
        cacc[1] = __builtin_amdgcn_mfma_f32_16x16x32_f16(pa, vb1, cacc[1], 0, 0, 0);
        cacc[2] = __builtin_amdgcn_mfma_f32_16x16x32_f16(pa, vb2, cacc[2], 0, 0, 0);
        cacc[3] = __builtin_amdgcn_mfma_f32_16x16x32_f16(pa, vb3, cacc[3], 0, 0, 0);
        vb0 = vn0; vb1 = vn1; vb2 = vn2; vb3 = vn3;
    }

#pragma unroll
    for (int tt = 0; tt < 8; ++tt) {
        half2v a = __builtin_bit_cast(half2v, sh[tt][0]);
        half2v b = __builtin_bit_cast(half2v, sh[tt][1]);
        float4 av;
        av.x = (float)a[0] * rinv; av.y = (float)a[1] * rinv;
        av.z = (float)b[0] * rinv; av.w = (float)b[1] * rinv;
        *reinterpret_cast<float4*>(&attn_out[rowbase + w * 128 + tt * 16 + lg * 4]) = av;
    }

    __syncthreads();
#pragma unroll
    for (int nt = 0; nt < 4; ++nt)
#pragma unroll
        for (int r = 0; r < 4; ++r)
            u.ctxbuf[w][lg * 4 + r][nt * 16 + lr] = cacc[nt][r];
    __syncthreads();
    if (tid < 256) {
        int e = tid * 4;
        int q = e >> 6, n = e & 63;
        float gs = 0.f;
#pragma unroll
        for (int ww = 0; ww < 8; ++ww) gs += red[1][ww][q];
        float rq = 1.0f / gs;
        float4 o = {0.f, 0.f, 0.f, 0.f};
#pragma unroll
        for (int ww = 0; ww < 8; ++ww) {
            float4 a = *reinterpret_cast<float4*>(&u.ctxbuf[ww][q][n]);
            o.x += a.x; o.y += a.y; o.z += a.z; o.w += a.w;
        }
        o.x *= rq; o.y *= rq; o.z *= rq; o.w *= rq;
        *reinterpret_cast<float4*>(&ctx_out[((size_t)bh * L_ + q0 + q) * DK_ + n]) = o;
    }
}

extern "C" void kernel_launch(void* const* d_in, const int* in_sizes, int n_in,
                              void* d_out, int out_size, void* d_ws, size_t ws_size,
                              hipStream_t stream) {
    const float* Q = (const float*)d_in[0];
    const float* K = (const float*)d_in[1];
    const float* V = (const float*)d_in[2];
    const int* mask = (const int*)d_in[3];
    float* ctx_out = (float*)d_out;
    float* attn_out = ctx_out + (size_t)BH_ * L_ * DK_;

    unsigned short* Kh = (unsigned short*)d_ws;
    unsigned short* Vt = Kh + (size_t)BH_ * L_ * DK_;

    hipLaunchKernelGGL(prep_k, dim3(4096), dim3(256), 0, stream, K, Kh);
    hipLaunchKernelGGL(prep_v, dim3(1024), dim3(256), 0, stream, V, Vt);
    hipLaunchKernelGGL(attn_a, dim3(64, 22), dim3(256), 0, stream,
                       Q, mask, Kh, Vt, ctx_out, attn_out);
    hipLaunchKernelGGL(attn_b, dim3(64, 21), dim3(256), 0, stream,
                       Q, mask, Kh, Vt, ctx_out, attn_out);
    hipLaunchKernelGGL(attn_c, dim3(64, 21), dim3(512), 0, stream,
                       Q, mask, Kh, Vt, ctx_out, attn_out);
}

// Round 10
// 273.590 us; speedup vs baseline: 1.2156x; 1.2156x over previous
//
#include <hip/hip_runtime.h>
#include <hip/hip_bf16.h>

typedef _Float16 half8 __attribute__((ext_vector_type(8)));
typedef _Float16 half2v __attribute__((ext_vector_type(2)));
typedef __fp16 fp16x2 __attribute__((ext_vector_type(2)));
typedef float f32x4 __attribute__((ext_vector_type(4)));

#define BH_ 64
#define L_ 1024
#define DK_ 64

__device__ __forceinline__ unsigned short f2h(float f) {
    _Float16 h = (_Float16)f;
    return __builtin_bit_cast(unsigned short, h);
}
__device__ __forceinline__ unsigned int pk2h(float a, float b) {
    fp16x2 h = __builtin_amdgcn_cvt_pkrtz(a, b);
    return __builtin_bit_cast(unsigned int, h);
}

// ---------------- prep: K -> fp16 ----------------
__global__ void prep_k(const float* __restrict__ K, unsigned short* __restrict__ Kh) {
    int idx = blockIdx.x * 256 + threadIdx.x;
    float4 v = reinterpret_cast<const float4*>(K)[idx];
    ushort4 o;
    o.x = f2h(v.x); o.y = f2h(v.y); o.z = f2h(v.z); o.w = f2h(v.w);
    reinterpret_cast<ushort4*>(Kh)[idx] = o;
}

// ---------------- prep: V -> Vt fp16 transposed [bh][n][k] ----------------
__global__ void prep_v(const float* __restrict__ V, unsigned short* __restrict__ Vt) {
    __shared__ float lds[64][65];
    int bh = blockIdx.x >> 4, kt = blockIdx.x & 15;
    int t = threadIdx.x;
    const float* Vb = V + ((size_t)bh * L_ + kt * 64) * DK_;
#pragma unroll
    for (int it = 0; it < 4; ++it) {
        int idx = it * 256 + t;
        int row = idx >> 4, c4 = idx & 15;
        float4 v = reinterpret_cast<const float4*>(Vb + (size_t)row * DK_)[c4];
        lds[row][c4 * 4 + 0] = v.x; lds[row][c4 * 4 + 1] = v.y;
        lds[row][c4 * 4 + 2] = v.z; lds[row][c4 * 4 + 3] = v.w;
    }
    __syncthreads();
    unsigned short* Vtb = Vt + (size_t)bh * 64 * L_ + kt * 64;
#pragma unroll
    for (int it = 0; it < 4; ++it) {
        int idx = it * 256 + t;
        int n = idx >> 4, c4 = idx & 15;
        ushort4 o;
        o.x = f2h(lds[c4 * 4 + 0][n]);
        o.y = f2h(lds[c4 * 4 + 1][n]);
        o.z = f2h(lds[c4 * 4 + 2][n]);
        o.w = f2h(lds[c4 * 4 + 3][n]);
        *reinterpret_cast<ushort4*>(Vtb + (size_t)n * L_ + c4 * 4) = o;
    }
}

// ---------------- main fused attention ----------------
// WG = 16 q-rows, 4 waves; wave w owns k in [w*256, w*256+256).
// ALL HBM streams are WG-contiguous 64KB tiles:
//  - mask: cooperative load (256B/thread contiguous) -> bit-pack -> LDS
//  - attn: p lives in swizzled LDS [16][1024] fp16; store pass writes
//    fp32 rows with 256B/thread contiguous => 64KB contiguous per WG.
__global__ __launch_bounds__(256, 4) void attn_main(
    const float* __restrict__ Q, const int* __restrict__ mask,
    const unsigned short* __restrict__ Kh, const unsigned short* __restrict__ Vt,
    float* __restrict__ ctx_out, float* __restrict__ attn_out)
{
    const int qt = blockIdx.x, bh = blockIdx.y;
    const int tid = threadIdx.x;
    const int w = tid >> 6;
    const int lane = tid & 63;
    const int lg = lane >> 4, lr = lane & 15;
    const int q0 = qt * 16;

    __shared__ unsigned int mbits[16][33];
    __shared__ float red[2][4][16];
    __shared__ union {
        unsigned short p[16][1024];   // swizzled: byte = row*2048 + (col*2 ^ ((row&7)<<4))
        float ctxbuf[4][16][68];
    } u;

    // swizzled p-LDS address (G4 XOR swizzle to kill the stride-2KB conflict)
    auto paddr = [&](int row, int col) -> unsigned short* {
        unsigned byte = (unsigned)row * 2048u +
                        (((unsigned)col * 2u) ^ (((unsigned)(row & 7)) << 4));
        return (unsigned short*)((char*)&u.p[0][0] + byte);
    };

    // ---- phase 0: cooperative, CONTIGUOUS mask tile load + bit-pack ----
    {
        int row = tid >> 4, cb = tid & 15;   // thread owns 64 ints of one row
        const int* mrow = mask + ((size_t)bh * L_ + q0 + row) * L_ + cb * 64;
        unsigned w0 = 0, w1 = 0;
#pragma unroll
        for (int j = 0; j < 8; ++j) {
            int4 v = *reinterpret_cast<const int4*>(mrow + j * 4);
            w0 |= (unsigned(v.x != 0) << (j * 4 + 0))
                | (unsigned(v.y != 0) << (j * 4 + 1))
                | (unsigned(v.z != 0) << (j * 4 + 2))
                | (unsigned(v.w != 0) << (j * 4 + 3));
        }
#pragma unroll
        for (int j = 0; j < 8; ++j) {
            int4 v = *reinterpret_cast<const int4*>(mrow + 32 + j * 4);
            w1 |= (unsigned(v.x != 0) << (j * 4 + 0))
                | (unsigned(v.y != 0) << (j * 4 + 1))
                | (unsigned(v.z != 0) << (j * 4 + 2))
                | (unsigned(v.w != 0) << (j * 4 + 3));
        }
        mbits[row][cb * 2] = w0;
        mbits[row][cb * 2 + 1] = w1;
    }

    // Q B-frag: lane holds Q[q0+lr][f*32 + lg*8 + j], fp16
    half8 qh[2];
    {
        const float* qp = Q + ((size_t)bh * L_ + q0 + lr) * DK_ + lg * 8;
#pragma unroll
        for (int f = 0; f < 2; ++f) {
            float4 a = *reinterpret_cast<const float4*>(qp + f * 32);
            float4 b = *reinterpret_cast<const float4*>(qp + f * 32 + 4);
            qh[f][0] = (_Float16)a.x; qh[f][1] = (_Float16)a.y;
            qh[f][2] = (_Float16)a.z; qh[f][3] = (_Float16)a.w;
            qh[f][4] = (_Float16)b.x; qh[f][5] = (_Float16)b.y;
            qh[f][6] = (_Float16)b.z; qh[f][7] = (_Float16)b.w;
        }
    }
    __syncthreads();   // mbits ready

    // per-lane mask words: row lr, cols [w*256, w*256+256) = words w*8..w*8+7
    unsigned int mw[8];
#pragma unroll
    for (int i = 0; i < 8; ++i) mw[i] = mbits[lr][w * 8 + i];

    // ---- QK^T: K depth-2 prefetch (L2-resident), mask from registers ----
    const unsigned short* kp = Kh + ((size_t)bh * L_ + w * 256 + lr) * DK_ + lg * 8;
    unsigned int sh[16][2];
    float mx = -INFINITY;

    half8 kc0 = *reinterpret_cast<const half8*>(kp);
    half8 kc1 = *reinterpret_cast<const half8*>(kp + 32);

#pragma unroll
    for (int tt = 0; tt < 16; ++tt) {
        half8 kn0 = kc0, kn1 = kc1;
        if (tt < 15) {
            kn0 = *reinterpret_cast<const half8*>(kp + (tt + 1) * 1024);
            kn1 = *reinterpret_cast<const half8*>(kp + (tt + 1) * 1024 + 32);
        }
        f32x4 acc = {0.f, 0.f, 0.f, 0.f};
        acc = __builtin_amdgcn_mfma_f32_16x16x32_f16(kc0, qh[0], acc, 0, 0, 0);
        acc = __builtin_amdgcn_mfma_f32_16x16x32_f16(kc1, qh[1], acc, 0, 0, 0);
        const unsigned int word = mw[tt >> 1];
        const unsigned int sh4 = (tt & 1) * 16 + lg * 4;
        float s0 = ((word >> (sh4 + 0)) & 1u) ? -INFINITY : 0.25f * acc[0];
        float s1 = ((word >> (sh4 + 1)) & 1u) ? -INFINITY : 0.25f * acc[1];
        float s2 = ((word >> (sh4 + 2)) & 1u) ? -INFINITY : 0.25f * acc[2];
        float s3 = ((word >> (sh4 + 3)) & 1u) ? -INFINITY : 0.25f * acc[3];
        sh[tt][0] = pk2h(s0, s1);
        sh[tt][1] = pk2h(s2, s3);
        mx = fmaxf(mx, fmaxf(fmaxf(s0, s1), fmaxf(s2, s3)));
        kc0 = kn0; kc1 = kn1;
    }

    // ---- softmax: row max across lg groups, then across waves ----
    mx = fmaxf(mx, __shfl_xor(mx, 16));
    mx = fmaxf(mx, __shfl_xor(mx, 32));
    if (lane < 16) red[0][w][lr] = mx;
    __syncthreads();
    const float gm = fmaxf(fmaxf(red[0][0][lr], red[0][1][lr]),
                           fmaxf(red[0][2][lr], red[0][3][lr]));

    // ---- exp + row sum; p stays packed fp16 (unnormalized) ----
    float lsum = 0.f;
#pragma unroll
    for (int tt = 0; tt < 16; ++tt) {
        half2v a = __builtin_bit_cast(half2v, sh[tt][0]);
        half2v b = __builtin_bit_cast(half2v, sh[tt][1]);
        float p0 = __expf((float)a[0] - gm);
        float p1 = __expf((float)a[1] - gm);
        float p2 = __expf((float)b[0] - gm);
        float p3 = __expf((float)b[1] - gm);
        lsum += (p0 + p1) + (p2 + p3);
        sh[tt][0] = pk2h(p0, p1);
        sh[tt][1] = pk2h(p2, p3);
    }
    lsum += __shfl_xor(lsum, 16);
    lsum += __shfl_xor(lsum, 32);
    if (lane < 16) red[1][w][lr] = lsum;

    // ---- p -> swizzled LDS (wave-private strip; sh regs die here) ----
#pragma unroll
    for (int tt = 0; tt < 16; ++tt) {
        uint2 pr; pr.x = sh[tt][0]; pr.y = sh[tt][1];
        *reinterpret_cast<uint2*>(paddr(lr, w * 256 + tt * 16 + lg * 4)) = pr;
    }

    // ---- PV: read p from LDS (swizzled, conflict-light), V depth-1 prefetch ----
    const unsigned short* vp = Vt + ((size_t)bh * 64 + lr) * L_ + w * 256 + lg * 8;
    f32x4 cacc[4] = {{0,0,0,0},{0,0,0,0},{0,0,0,0},{0,0,0,0}};
    half8 vb0 = *reinterpret_cast<const half8*>(vp);
    half8 vb1 = *reinterpret_cast<const half8*>(vp + 16384);
    half8 vb2 = *reinterpret_cast<const half8*>(vp + 32768);
    half8 vb3 = *reinterpret_cast<const half8*>(vp + 49152);

#pragma unroll
    for (int c = 0; c < 8; ++c) {
        half8 vn0 = vb0, vn1 = vb1, vn2 = vb2, vn3 = vb3;
        if (c < 7) {
            vn0 = *reinterpret_cast<const half8*>(vp + (c + 1) * 32);
            vn1 = *reinterpret_cast<const half8*>(vp + 16384 + (c + 1) * 32);
            vn2 = *reinterpret_cast<const half8*>(vp + 32768 + (c + 1) * 32);
            vn3 = *reinterpret_cast<const half8*>(vp + 49152 + (c + 1) * 32);
        }
        half8 pa = *reinterpret_cast<const half8*>(paddr(lr, w * 256 + c * 32 + lg * 8));
        cacc[0] = __builtin_amdgcn_mfma_f32_16x16x32_f16(pa, vb0, cacc[0], 0, 0, 0);
        cacc[1] = __builtin_amdgcn_mfma_f32_16x16x32_f16(pa, vb1, cacc[1], 0, 0, 0);
        cacc[2] = __builtin_amdgcn_mfma_f32_16x16x32_f16(pa, vb2, cacc[2], 0, 0, 0);
        cacc[3] = __builtin_amdgcn_mfma_f32_16x16x32_f16(pa, vb3, cacc[3], 0, 0, 0);
        vb0 = vn0; vb1 = vn1; vb2 = vn2; vb3 = vn3;
    }

    __syncthreads();   // all p strips + red[1] visible to everyone

    // ---- attn store pass: CONTIGUOUS 64KB tile per WG ----
    // thread t: row q=t>>4, 64-col block cb=t&15 -> 256B contiguous per thread.
    {
        int q = tid >> 4, cb = tid & 15;
        float rq = 1.0f / (red[1][0][q] + red[1][1][q] + red[1][2][q] + red[1][3][q]);
        float* orow = attn_out + ((size_t)bh * L_ + q0 + q) * L_ + cb * 64;
#pragma unroll
        for (int j = 0; j < 8; ++j) {
            half8 v = *reinterpret_cast<const half8*>(paddr(q, cb * 64 + j * 8));
            float4 o0, o1;
            o0.x = (float)v[0] * rq; o0.y = (float)v[1] * rq;
            o0.z = (float)v[2] * rq; o0.w = (float)v[3] * rq;
            o1.x = (float)v[4] * rq; o1.y = (float)v[5] * rq;
            o1.z = (float)v[6] * rq; o1.w = (float)v[7] * rq;
            *reinterpret_cast<float4*>(orow + j * 8) = o0;
            *reinterpret_cast<float4*>(orow + j * 8 + 4) = o1;
        }
    }

    __syncthreads();   // store pass done reading u.p -> safe to overwrite

    // ---- combine partial contexts across waves, normalize by 1/sum ----
#pragma unroll
    for (int nt = 0; nt < 4; ++nt)
#pragma unroll
        for (int r = 0; r < 4; ++r)
            u.ctxbuf[w][lg * 4 + r][nt * 16 + lr] = cacc[nt][r];
    __syncthreads();
    {
        int e = tid * 4;
        int q = e >> 6, n = e & 63;
        float gs = red[1][0][q] + red[1][1][q] + red[1][2][q] + red[1][3][q];
        float rq = 1.0f / gs;
        float4 a0 = *reinterpret_cast<float4*>(&u.ctxbuf[0][q][n]);
        float4 a1 = *reinterpret_cast<float4*>(&u.ctxbuf[1][q][n]);
        float4 a2 = *reinterpret_cast<float4*>(&u.ctxbuf[2][q][n]);
        float4 a3 = *reinterpret_cast<float4*>(&u.ctxbuf[3][q][n]);
        float4 o;
        o.x = (a0.x + a1.x + a2.x + a3.x) * rq;
        o.y = (a0.y + a1.y + a2.y + a3.y) * rq;
        o.z = (a0.z + a1.z + a2.z + a3.z) * rq;
        o.w = (a0.w + a1.w + a2.w + a3.w) * rq;
        *reinterpret_cast<float4*>(&ctx_out[((size_t)bh * L_ + q0 + q) * DK_ + n]) = o;
    }
}

extern "C" void kernel_launch(void* const* d_in, const int* in_sizes, int n_in,
                              void* d_out, int out_size, void* d_ws, size_t ws_size,
                              hipStream_t stream) {
    const float* Q = (const float*)d_in[0];
    const float* K = (const float*)d_in[1];
    const float* V = (const float*)d_in[2];
    const int* mask = (const int*)d_in[3];
    float* ctx_out = (float*)d_out;
    float* attn_out = ctx_out + (size_t)BH_ * L_ * DK_;

    unsigned short* Kh = (unsigned short*)d_ws;
    unsigned short* Vt = Kh + (size_t)BH_ * L_ * DK_;

    hipLaunchKernelGGL(prep_k, dim3(4096), dim3(256), 0, stream, K, Kh);
    hipLaunchKernelGGL(prep_v, dim3(1024), dim3(256), 0, stream, V, Vt);
    hipLaunchKernelGGL(attn_main, dim3(64, 64), dim3(256), 0, stream,
                       Q, mask, Kh, Vt, ctx_out, attn_out);
}

// Round 11
// 206.738 us; speedup vs baseline: 1.6087x; 1.3234x over previous
//
#include <hip/hip_runtime.h>
#include <hip/hip_bf16.h>

typedef _Float16 half8 __attribute__((ext_vector_type(8)));
typedef _Float16 half4 __attribute__((ext_vector_type(4)));
typedef _Float16 half2v __attribute__((ext_vector_type(2)));
typedef __fp16 fp16x2 __attribute__((ext_vector_type(2)));
typedef float f32x4 __attribute__((ext_vector_type(4)));

#define BH_ 64
#define L_ 1024
#define DK_ 64

__device__ __forceinline__ unsigned short f2h(float f) {
    _Float16 h = (_Float16)f;
    return __builtin_bit_cast(unsigned short, h);
}
__device__ __forceinline__ unsigned int pk2h(float a, float b) {
    fp16x2 h = __builtin_amdgcn_cvt_pkrtz(a, b);
    return __builtin_bit_cast(unsigned int, h);
}

// ---------------- prep: K -> fp16 ----------------
__global__ void prep_k(const float* __restrict__ K, unsigned short* __restrict__ Kh) {
    int idx = blockIdx.x * 256 + threadIdx.x;
    float4 v = reinterpret_cast<const float4*>(K)[idx];
    ushort4 o;
    o.x = f2h(v.x); o.y = f2h(v.y); o.z = f2h(v.z); o.w = f2h(v.w);
    reinterpret_cast<ushort4*>(Kh)[idx] = o;
}

// ---------------- prep: V -> Vt fp16 transposed [bh][n][k] ----------------
__global__ void prep_v(const float* __restrict__ V, unsigned short* __restrict__ Vt) {
    __shared__ float lds[64][65];
    int bh = blockIdx.x >> 4, kt = blockIdx.x & 15;
    int t = threadIdx.x;
    const float* Vb = V + ((size_t)bh * L_ + kt * 64) * DK_;
#pragma unroll
    for (int it = 0; it < 4; ++it) {
        int idx = it * 256 + t;
        int row = idx >> 4, c4 = idx & 15;
        float4 v = reinterpret_cast<const float4*>(Vb + (size_t)row * DK_)[c4];
        lds[row][c4 * 4 + 0] = v.x; lds[row][c4 * 4 + 1] = v.y;
        lds[row][c4 * 4 + 2] = v.z; lds[row][c4 * 4 + 3] = v.w;
    }
    __syncthreads();
    unsigned short* Vtb = Vt + (size_t)bh * 64 * L_ + kt * 64;
#pragma unroll
    for (int it = 0; it < 4; ++it) {
        int idx = it * 256 + t;
        int n = idx >> 4, c4 = idx & 15;
        ushort4 o;
        o.x = f2h(lds[c4 * 4 + 0][n]);
        o.y = f2h(lds[c4 * 4 + 1][n]);
        o.z = f2h(lds[c4 * 4 + 2][n]);
        o.w = f2h(lds[c4 * 4 + 3][n]);
        *reinterpret_cast<ushort4*>(Vtb + (size_t)n * L_ + c4 * 4) = o;
    }
}

// ---------------- main fused attention ----------------
// WG = 16 q-rows, 4 waves; wave w owns k in [w*256, w*256+256) for compute.
// DRAM streams are WAVE-SEQUENTIAL ROW BURSTS (R10 post-mortem: 4KB-stride
// row interleave = HBM channel/page thrash; per-WG contiguity with 256B lane
// granularity = sector fragmentation; the fix is 1KB-contiguous per
// instruction, 4KB-sequential per wave):
//  - mask: wave w reads rows w*4..w*4+3, 4x int4/lane contiguous per row
//  - attn: wave w stores rows w*4..w*4+3, 4x float4/lane contiguous per row
__global__ __launch_bounds__(256, 4) void attn_main(
    const float* __restrict__ Q, const int* __restrict__ mask,
    const unsigned short* __restrict__ Kh, const unsigned short* __restrict__ Vt,
    float* __restrict__ ctx_out, float* __restrict__ attn_out)
{
    const int qt = blockIdx.x, bh = blockIdx.y;
    const int tid = threadIdx.x;
    const int w = tid >> 6;
    const int lane = tid & 63;
    const int lg = lane >> 4, lr = lane & 15;
    const int q0 = qt * 16;

    __shared__ unsigned char mnib[16][272];   // nibble-per-4cols, padded stride
    __shared__ float red[2][4][16];
    __shared__ union {
        unsigned short p[16][1024];  // swizzled: byte = row*2048 + (col*2 ^ ((row&7)<<4))
        float ctxbuf[4][16][68];
    } u;

    auto paddr = [&](int row, int col) -> unsigned short* {
        unsigned byte = (unsigned)row * 2048u +
                        (((unsigned)col * 2u) ^ (((unsigned)(row & 7)) << 4));
        return (unsigned short*)((char*)&u.p[0][0] + byte);
    };

    // ---- phase 0: mask rows, wave-sequential bursts -> nibble LDS ----
#pragma unroll
    for (int rr = 0; rr < 4; ++rr) {
        const int row = w * 4 + rr;
        const int* mrow = mask + ((size_t)bh * L_ + q0 + row) * L_;
#pragma unroll
        for (int j = 0; j < 4; ++j) {         // 4 x 1KB contiguous per row
            int4 v = *reinterpret_cast<const int4*>(mrow + j * 256 + lane * 4);
            unsigned nib = unsigned(v.x != 0)
                         | (unsigned(v.y != 0) << 1)
                         | (unsigned(v.z != 0) << 2)
                         | (unsigned(v.w != 0) << 3);
            mnib[row][j * 64 + lane] = (unsigned char)nib;
        }
    }

    // Q B-frag: lane holds Q[q0+lr][f*32 + lg*8 + j], fp16
    half8 qh[2];
    {
        const float* qp = Q + ((size_t)bh * L_ + q0 + lr) * DK_ + lg * 8;
#pragma unroll
        for (int f = 0; f < 2; ++f) {
            float4 a = *reinterpret_cast<const float4*>(qp + f * 32);
            float4 b = *reinterpret_cast<const float4*>(qp + f * 32 + 4);
            qh[f][0] = (_Float16)a.x; qh[f][1] = (_Float16)a.y;
            qh[f][2] = (_Float16)a.z; qh[f][3] = (_Float16)a.w;
            qh[f][4] = (_Float16)b.x; qh[f][5] = (_Float16)b.y;
            qh[f][6] = (_Float16)b.z; qh[f][7] = (_Float16)b.w;
        }
    }
    __syncthreads();   // mnib ready (cross-wave: QK reads row lr)

    // ---- QK^T: K depth-2 prefetch (L2-resident), mask nibble per tile ----
    const unsigned short* kp = Kh + ((size_t)bh * L_ + w * 256 + lr) * DK_ + lg * 8;
    const unsigned char* mn = &mnib[lr][w * 64];
    unsigned int sh[16][2];
    float mx = -INFINITY;

    half8 kc0 = *reinterpret_cast<const half8*>(kp);
    half8 kc1 = *reinterpret_cast<const half8*>(kp + 32);

#pragma unroll
    for (int tt = 0; tt < 16; ++tt) {
        half8 kn0 = kc0, kn1 = kc1;
        if (tt < 15) {
            kn0 = *reinterpret_cast<const half8*>(kp + (tt + 1) * 1024);
            kn1 = *reinterpret_cast<const half8*>(kp + (tt + 1) * 1024 + 32);
        }
        f32x4 acc = {0.f, 0.f, 0.f, 0.f};
        acc = __builtin_amdgcn_mfma_f32_16x16x32_f16(kc0, qh[0], acc, 0, 0, 0);
        acc = __builtin_amdgcn_mfma_f32_16x16x32_f16(kc1, qh[1], acc, 0, 0, 0);
        // broadcast u32 = 4 lg-nibbles of tile tt; extract this lane's nibble
        unsigned nv = *reinterpret_cast<const unsigned int*>(&mn[tt * 4]);
        unsigned nib = (nv >> (lg * 8)) & 0xFu;
        float s0 = (nib & 1u) ? -INFINITY : 0.25f * acc[0];
        float s1 = (nib & 2u) ? -INFINITY : 0.25f * acc[1];
        float s2 = (nib & 4u) ? -INFINITY : 0.25f * acc[2];
        float s3 = (nib & 8u) ? -INFINITY : 0.25f * acc[3];
        sh[tt][0] = pk2h(s0, s1);
        sh[tt][1] = pk2h(s2, s3);
        mx = fmaxf(mx, fmaxf(fmaxf(s0, s1), fmaxf(s2, s3)));
        kc0 = kn0; kc1 = kn1;
    }

    // ---- softmax: row max across lg groups, then across waves ----
    mx = fmaxf(mx, __shfl_xor(mx, 16));
    mx = fmaxf(mx, __shfl_xor(mx, 32));
    if (lane < 16) red[0][w][lr] = mx;
    __syncthreads();
    const float gm = fmaxf(fmaxf(red[0][0][lr], red[0][1][lr]),
                           fmaxf(red[0][2][lr], red[0][3][lr]));

    // ---- exp + row sum; p stays packed fp16 (unnormalized) ----
    float lsum = 0.f;
#pragma unroll
    for (int tt = 0; tt < 16; ++tt) {
        half2v a = __builtin_bit_cast(half2v, sh[tt][0]);
        half2v b = __builtin_bit_cast(half2v, sh[tt][1]);
        float p0 = __expf((float)a[0] - gm);
        float p1 = __expf((float)a[1] - gm);
        float p2 = __expf((float)b[0] - gm);
        float p3 = __expf((float)b[1] - gm);
        lsum += (p0 + p1) + (p2 + p3);
        sh[tt][0] = pk2h(p0, p1);
        sh[tt][1] = pk2h(p2, p3);
    }
    lsum += __shfl_xor(lsum, 16);
    lsum += __shfl_xor(lsum, 32);
    if (lane < 16) red[1][w][lr] = lsum;

    // ---- p -> swizzled LDS (wave-private strip) ----
#pragma unroll
    for (int tt = 0; tt < 16; ++tt) {
        uint2 pr; pr.x = sh[tt][0]; pr.y = sh[tt][1];
        *reinterpret_cast<uint2*>(paddr(lr, w * 256 + tt * 16 + lg * 4)) = pr;
    }

    // ---- PV: read p from LDS, V depth-1 prefetch (L2-resident) ----
    const unsigned short* vp = Vt + ((size_t)bh * 64 + lr) * L_ + w * 256 + lg * 8;
    f32x4 cacc[4] = {{0,0,0,0},{0,0,0,0},{0,0,0,0},{0,0,0,0}};
    half8 vb0 = *reinterpret_cast<const half8*>(vp);
    half8 vb1 = *reinterpret_cast<const half8*>(vp + 16384);
    half8 vb2 = *reinterpret_cast<const half8*>(vp + 32768);
    half8 vb3 = *reinterpret_cast<const half8*>(vp + 49152);

#pragma unroll
    for (int c = 0; c < 8; ++c) {
        half8 vn0 = vb0, vn1 = vb1, vn2 = vb2, vn3 = vb3;
        if (c < 7) {
            vn0 = *reinterpret_cast<const half8*>(vp + (c + 1) * 32);
            vn1 = *reinterpret_cast<const half8*>(vp + 16384 + (c + 1) * 32);
            vn2 = *reinterpret_cast<const half8*>(vp + 32768 + (c + 1) * 32);
            vn3 = *reinterpret_cast<const half8*>(vp + 49152 + (c + 1) * 32);
        }
        half8 pa = *reinterpret_cast<const half8*>(paddr(lr, w * 256 + c * 32 + lg * 8));
        cacc[0] = __builtin_amdgcn_mfma_f32_16x16x32_f16(pa, vb0, cacc[0], 0, 0, 0);
        cacc[1] = __builtin_amdgcn_mfma_f32_16x16x32_f16(pa, vb1, cacc[1], 0, 0, 0);
        cacc[2] = __builtin_amdgcn_mfma_f32_16x16x32_f16(pa, vb2, cacc[2], 0, 0, 0);
        cacc[3] = __builtin_amdgcn_mfma_f32_16x16x32_f16(pa, vb3, cacc[3], 0, 0, 0);
        vb0 = vn0; vb1 = vn1; vb2 = vn2; vb3 = vn3;
    }

    __syncthreads();   // all p strips + red[1] visible

    // ---- attn store pass: wave-sequential row bursts ----
    // wave w stores rows w*4..w*4+3; per row: 4 x (1KB contiguous, lane*16B)
#pragma unroll
    for (int rr = 0; rr < 4; ++rr) {
        const int q = w * 4 + rr;
        const float rq = 1.0f / (red[1][0][q] + red[1][1][q] +
                                 red[1][2][q] + red[1][3][q]);
        float* orow = attn_out + ((size_t)bh * L_ + q0 + q) * L_;
#pragma unroll
        for (int i = 0; i < 4; ++i) {
            const int col = i * 256 + lane * 4;
            half4 v = *reinterpret_cast<const half4*>(paddr(q, col));
            float4 o;
            o.x = (float)v[0] * rq; o.y = (float)v[1] * rq;
            o.z = (float)v[2] * rq; o.w = (float)v[3] * rq;
            *reinterpret_cast<float4*>(orow + col) = o;
        }
    }

    __syncthreads();   // store pass done reading u.p -> safe to overwrite

    // ---- combine partial contexts across waves, normalize by 1/sum ----
#pragma unroll
    for (int nt = 0; nt < 4; ++nt)
#pragma unroll
        for (int r = 0; r < 4; ++r)
            u.ctxbuf[w][lg * 4 + r][nt * 16 + lr] = cacc[nt][r];
    __syncthreads();
    {
        int e = tid * 4;
        int q = e >> 6, n = e & 63;
        float gs = red[1][0][q] + red[1][1][q] + red[1][2][q] + red[1][3][q];
        float rq = 1.0f / gs;
        float4 a0 = *reinterpret_cast<float4*>(&u.ctxbuf[0][q][n]);
        float4 a1 = *reinterpret_cast<float4*>(&u.ctxbuf[1][q][n]);
        float4 a2 = *reinterpret_cast<float4*>(&u.ctxbuf[2][q][n]);
        float4 a3 = *reinterpret_cast<float4*>(&u.ctxbuf[3][q][n]);
        float4 o;
        o.x = (a0.x + a1.x + a2.x + a3.x) * rq;
        o.y = (a0.y + a1.y + a2.y + a3.y) * rq;
        o.z = (a0.z + a1.z + a2.z + a3.z) * rq;
        o.w = (a0.w + a1.w + a2.w + a3.w) * rq;
        *reinterpret_cast<float4*>(&ctx_out[((size_t)bh * L_ + q0 + q) * DK_ + n]) = o;
    }
}

extern "C" void kernel_launch(void* const* d_in, const int* in_sizes, int n_in,
                              void* d_out, int out_size, void* d_ws, size_t ws_size,
                              hipStream_t stream) {
    const float* Q = (const float*)d_in[0];
    const float* K = (const float*)d_in[1];
    const float* V = (const float*)d_in[2];
    const int* mask = (const int*)d_in[3];
    float* ctx_out = (float*)d_out;
    float* attn_out = ctx_out + (size_t)BH_ * L_ * DK_;

    unsigned short* Kh = (unsigned short*)d_ws;
    unsigned short* Vt = Kh + (size_t)BH_ * L_ * DK_;

    hipLaunchKernelGGL(prep_k, dim3(4096), dim3(256), 0, stream, K, Kh);
    hipLaunchKernelGGL(prep_v, dim3(1024), dim3(256), 0, stream, V, Vt);
    hipLaunchKernelGGL(attn_main, dim3(64, 64), dim3(256), 0, stream,
                       Q, mask, Kh, Vt, ctx_out, attn_out);
}